// Round 1
// baseline (17300.407 us; speedup 1.0000x reference)
//
#include <hip/hip_runtime.h>
#include <hip/hip_bf16.h>

#define DH    64
#define INW   32
#define OUTW  8
#define WIDW  128
#define BATCH 128
#define SEQN  16
#define NSUB  4

// workspace offsets (in floats) for transposed weights
#define OFF_GW2T 0        // [k*4096 + r], 128x4096
#define OFF_FW0T 524288   // [k*128 + o], 65x128
#define OFF_GW0T 532608
#define OFF_FW1T 540928   // [k*128 + o], 128x128
#define OFF_GW1T 557312
#define OFF_FW2T 573696   // [k*64 + o], 128x64
#define OFF_RWHT 581888   // [k*64 + o], 64x64
#define OFF_RWXT 585984   // [k*64 + o], 32x64
#define OFF_OW0T 588032   // [k*128 + o], 64x128
#define OFF_OW1T 596224   // [k*128 + o], 128x128
#define OFF_OW2T 612608   // [k*8 + o], 128x8
#define WS_TOTAL 613632

__device__ __forceinline__ float fast_tanh(float x){
  float ax = fabsf(x);
  float e  = __expf(-2.f*ax);
  float r  = __fdividef(1.f - e, 1.f + e);
  return copysignf(r, x);
}
__device__ __forceinline__ float fast_silu(float x){
  return x * __fdividef(1.f, 1.f + __expf(-x));
}

__global__ void prep_transpose(const float* __restrict__ fw0, const float* __restrict__ fw1,
                               const float* __restrict__ fw2, const float* __restrict__ gw0,
                               const float* __restrict__ gw1, const float* __restrict__ gw2,
                               const float* __restrict__ rwh, const float* __restrict__ rwx,
                               const float* __restrict__ ow0, const float* __restrict__ ow1,
                               const float* __restrict__ ow2, float* __restrict__ ws)
{
  int i = blockIdx.x * 256 + threadIdx.x;
  if (i >= WS_TOTAL) return;
  if (i < OFF_FW0T){            // gw2T[k*4096 + r] = gw2[r*128 + k]
    int r = i & 4095, k = i >> 12;
    ws[i] = gw2[r*128 + k];
  } else if (i < OFF_GW0T){ int j=i-OFF_FW0T; int o=j&127, k=j>>7; ws[i]=fw0[o*65+k]; }
  else if (i < OFF_FW1T){ int j=i-OFF_GW0T; int o=j&127, k=j>>7; ws[i]=gw0[o*65+k]; }
  else if (i < OFF_GW1T){ int j=i-OFF_FW1T; int o=j&127, k=j>>7; ws[i]=fw1[o*128+k]; }
  else if (i < OFF_FW2T){ int j=i-OFF_GW1T; int o=j&127, k=j>>7; ws[i]=gw1[o*128+k]; }
  else if (i < OFF_RWHT){ int j=i-OFF_FW2T; int o=j&63,  k=j>>6; ws[i]=fw2[o*128+k]; }
  else if (i < OFF_RWXT){ int j=i-OFF_RWHT; int o=j&63,  k=j>>6; ws[i]=rwh[o*64+k]; }
  else if (i < OFF_OW0T){ int j=i-OFF_RWXT; int o=j&63,  k=j>>6; ws[i]=rwx[o*32+k]; }
  else if (i < OFF_OW1T){ int j=i-OFF_OW0T; int o=j&127, k=j>>7; ws[i]=ow0[o*64+k]; }
  else if (i < OFF_OW2T){ int j=i-OFF_OW1T; int o=j&127, k=j>>7; ws[i]=ow1[o*128+k]; }
  else                  { int j=i-OFF_OW2T; int o=j&7,   k=j>>3; ws[i]=ow2[o*128+k]; }
}

__global__ __launch_bounds__(256) void ace_main(
    const float* __restrict__ ts,
    const float* __restrict__ obs,
    const float* __restrict__ fb0, const float* __restrict__ fb1, const float* __restrict__ fb2,
    const float* __restrict__ gb0, const float* __restrict__ gb1, const float* __restrict__ gb2,
    const float* __restrict__ fsc, const float* __restrict__ gsc,
    const float* __restrict__ rnnb,
    const float* __restrict__ ob0, const float* __restrict__ ob1, const float* __restrict__ ob2,
    const float* __restrict__ ws,
    float* __restrict__ outp)
{
  // Tsit5 tableau (compile-time constants; loops over them fully unrolled)
  constexpr float ATc[5][5] = {
    {0.161f, 0.f, 0.f, 0.f, 0.f},
    {-0.008480655492356989f, 0.335480655492357f, 0.f, 0.f, 0.f},
    {2.8971530571054935f, -6.359448489975075f, 4.3622954328695815f, 0.f, 0.f},
    {5.325864828439257f, -11.748883564062828f, 7.4955393428898365f, -0.09249506636175525f, 0.f},
    {5.86145544294642f, -12.92096931784711f, 8.159367898576159f, -0.071584973281401f, -0.028269050394068383f}};
  constexpr float CTc[6] = {0.f, 0.161f, 0.327f, 0.9f, 0.9800255409045097f, 1.f};
  constexpr float BTc[6] = {0.09646076681806523f, 0.01f, 0.4798896504144996f,
                            1.379008574103742f, -3.290069515436081f, 2.324710524099774f};

  const int tid = threadIdx.x;
  const int b   = blockIdx.x;

  const float* gw2T = ws + OFF_GW2T;
  const float* fw0T = ws + OFF_FW0T;
  const float* gw0T = ws + OFF_GW0T;
  const float* fw1T = ws + OFF_FW1T;
  const float* gw1T = ws + OFF_GW1T;
  const float* fw2T = ws + OFF_FW2T;
  const float* rwhT = ws + OFF_RWHT;
  const float* rwxT = ws + OFF_RWXT;
  const float* ow0T = ws + OFF_OW0T;
  const float* ow1T = ws + OFF_OW1T;
  const float* ow2T = ws + OFF_OW2T;

  __shared__ float a_st[64*66];          // pitched 66 to break stride-64 bank conflicts
  __shared__ float h_st[DH];
  __shared__ float h_b[DH];
  __shared__ float inp[DH+1];
  __shared__ float kh[6][DH];
  __shared__ float zf0[WIDW], zg0[WIDW], zf1[WIDW], zg1[WIDW];
  __shared__ float red;

  float ka[6][16];   // per-thread a-rate stages: element e = i*256 + tid
  float a_b[16];     // per-thread a-state base
  float gb2r[16];
  #pragma unroll
  for (int i=0;i<16;++i) gb2r[i] = gb2[i*256 + tid];
  const float sf = fsc[0], sg = gsc[0];

  auto field_eval = [&](float t, float* khrow, float (&ka_out)[16]) {
    // requires: h_st, a_st current and visible (barrier done by caller)
    {
      const int row = tid >> 2, part = tid & 3;
      const float* ar = a_st + row*66;
      float m = -1e30f;
      #pragma unroll
      for (int jj=0;jj<16;++jj) m = fmaxf(m, ar[part + 4*jj]);
      m = fmaxf(m, __shfl_xor(m, 1, 64));
      m = fmaxf(m, __shfl_xor(m, 2, 64));
      float es = 0.f, hs = 0.f;
      #pragma unroll
      for (int jj=0;jj<16;++jj){
        int j = part + 4*jj;
        float e = __expf(ar[j] - m);
        es += e; hs += e * h_st[j];
      }
      es += __shfl_xor(es, 1, 64); es += __shfl_xor(es, 2, 64);
      hs += __shfl_xor(hs, 1, 64); hs += __shfl_xor(hs, 2, 64);
      if (part == 0) inp[row] = __fdividef(hs, es);
      if (tid == 0) inp[DH] = t;
    }
    __syncthreads();
    { // layer 0, f-net on waves 0-1, g-net on waves 2-3
      const int o = tid & 127;
      const float* wT = (tid < 128) ? fw0T : gw0T;
      const float* bb = (tid < 128) ? fb0 : gb0;
      float acc = bb[o];
      #pragma unroll 5
      for (int k=0;k<DH+1;++k) acc = fmaf(wT[k*128 + o], inp[k], acc);
      float* zo = (tid < 128) ? zf0 : zg0;
      zo[o] = fast_silu(acc);
    }
    __syncthreads();
    { // layer 1
      const int o = tid & 127;
      const float* wT = (tid < 128) ? fw1T : gw1T;
      const float* bb = (tid < 128) ? fb1 : gb1;
      const float* zi = (tid < 128) ? zf0 : zg0;
      float acc = bb[o];
      #pragma unroll 8
      for (int k=0;k<WIDW;++k) acc = fmaf(wT[k*128 + o], zi[k], acc);
      float* zo = (tid < 128) ? zf1 : zg1;
      zo[o] = fast_silu(acc);
    }
    __syncthreads();
    if (tid < 64){ // f head -> h_dot
      float acc = fb2[tid];
      #pragma unroll 8
      for (int k=0;k<WIDW;++k) acc = fmaf(fw2T[k*64 + tid], zf1[k], acc);
      khrow[tid] = sf * fast_tanh(acc);
    }
    { // g head: 4096x128 GEMV, 16 rows per thread, coalesced via gw2T
      float acc[16];
      #pragma unroll
      for (int i=0;i<16;++i) acc[i] = 0.f;
      #pragma unroll 2
      for (int k=0;k<WIDW;++k){
        float zk = zg1[k];
        const float* wp = gw2T + k*4096 + tid;
        #pragma unroll
        for (int i=0;i<16;++i) acc[i] = fmaf(wp[i*256], zk, acc[i]);
      }
      #pragma unroll
      for (int i=0;i<16;++i) ka_out[i] = sg * fast_tanh(acc[i] + gb2r[i]);
    }
    // no trailing barrier: RK update only touches own-thread kh row / ka regs,
    // and the next eval is preceded by a barrier.
  };

  auto attn_from_h = [&](){
    // h_b written (wave0) before entry; internal barrier publishes it
    if (tid < 64){
      float v = h_b[tid]; v = v*v;
      #pragma unroll
      for (int off=32; off>0; off>>=1) v += __shfl_xor(v, off, 64);
      if (tid == 0) red = __fdividef(1.f, sqrtf(v) + 1e-8f);
    }
    __syncthreads();
    const float inv = red;
    #pragma unroll
    for (int i=0;i<16;++i){
      int e = i*256 + tid;
      a_b[i] = (h_b[e>>6] * inv) * (h_b[e & 63] * inv);
    }
  };

  // ---- init: h0 = tanh(rnn_wx @ obs[0] + rnn_b); a0 = attn(h0)
  {
    float hnew = 0.f;
    if (tid < 64){
      float acc = rnnb[tid];
      const float* x0 = obs + b*(SEQN*INW);
      #pragma unroll
      for (int k=0;k<INW;++k) acc = fmaf(rwxT[k*64 + tid], x0[k], acc);
      hnew = fast_tanh(acc);
      h_b[tid] = hnew;
    }
    __syncthreads();
    attn_from_h();
  }

  for (int n=0; n<SEQN-1; ++n){
    const float t0 = ts[b*SEQN + n];
    const float t1 = ts[b*SEQN + n + 1];
    const float dtn = (t1 - t0) * 0.25f;

    for (int isub=0; isub<NSUB; ++isub){
      const float tb = fmaf((float)isub, dtn, t0);
      // stage buffers <- base state
      if (tid < 64) h_st[tid] = h_b[tid];
      #pragma unroll
      for (int i=0;i<16;++i){
        int e = i*256 + tid;
        a_st[(e>>6)*66 + (e&63)] = a_b[i];
      }
      __syncthreads();
      field_eval(tb, kh[0], ka[0]);

      #pragma unroll
      for (int s=0;s<5;++s){
        if (tid < 64){
          float acc = 0.f;
          #pragma unroll
          for (int j=0;j<=s;++j) acc = fmaf(ATc[s][j], kh[j][tid], acc);
          h_st[tid] = fmaf(dtn, acc, h_b[tid]);
        }
        #pragma unroll
        for (int i=0;i<16;++i){
          float acc = 0.f;
          #pragma unroll
          for (int j=0;j<=s;++j) acc = fmaf(ATc[s][j], ka[j][i], acc);
          int e = i*256 + tid;
          a_st[(e>>6)*66 + (e&63)] = fmaf(dtn, acc, a_b[i]);
        }
        __syncthreads();
        field_eval(fmaf(CTc[s+1], dtn, tb), kh[s+1], ka[s+1]);
      }

      // final combine
      if (tid < 64){
        float acc = 0.f;
        #pragma unroll
        for (int j=0;j<6;++j) acc = fmaf(BTc[j], kh[j][tid], acc);
        h_b[tid] = fmaf(dtn, acc, h_b[tid]);
      }
      #pragma unroll
      for (int i=0;i<16;++i){
        float acc = 0.f;
        #pragma unroll
        for (int j=0;j<6;++j) acc = fmaf(BTc[j], ka[j][i], acc);
        a_b[i] = fmaf(dtn, acc, a_b[i]);
      }
    }

    // ---- RNN boundary: h <- tanh(Wh h' + Wx x + b); a <- attn(h)
    {
      float hnew = 0.f;
      if (tid < 64){
        float acc = rnnb[tid];
        const float* x = obs + (b*SEQN + (n+1))*INW;
        #pragma unroll
        for (int k=0;k<INW;++k) acc = fmaf(rwxT[k*64 + tid], x[k], acc);
        #pragma unroll 8
        for (int k=0;k<DH;++k)  acc = fmaf(rwhT[k*64 + tid], h_b[k], acc);
        hnew = fast_tanh(acc);
      }
      __syncthreads();            // all reads of old h_b complete
      if (tid < 64) h_b[tid] = hnew;
      attn_from_h();              // internal barrier publishes h_b/red
    }
  }

  // ---- output MLP (tanh activations)
  __syncthreads();
  if (tid < 128){
    float acc = ob0[tid];
    #pragma unroll 8
    for (int k=0;k<DH;++k) acc = fmaf(ow0T[k*128 + tid], h_b[k], acc);
    zf0[tid] = fast_tanh(acc);
  }
  __syncthreads();
  if (tid < 128){
    float acc = ob1[tid];
    #pragma unroll 8
    for (int k=0;k<WIDW;++k) acc = fmaf(ow1T[k*128 + tid], zf0[k], acc);
    zf1[tid] = fast_tanh(acc);
  }
  __syncthreads();
  if (tid < OUTW){
    float acc = ob2[tid];
    #pragma unroll 8
    for (int k=0;k<WIDW;++k) acc = fmaf(ow2T[k*8 + tid], zf1[k], acc);
    outp[b*OUTW + tid] = acc;
  }
}

extern "C" void kernel_launch(void* const* d_in, const int* in_sizes, int n_in,
                              void* d_out, int out_size, void* d_ws, size_t ws_size,
                              hipStream_t stream)
{
  const float* ts   = (const float*)d_in[0];
  const float* obs  = (const float*)d_in[1];
  const float* fw0  = (const float*)d_in[2];
  const float* fb0  = (const float*)d_in[3];
  const float* fw1  = (const float*)d_in[4];
  const float* fb1  = (const float*)d_in[5];
  const float* fw2  = (const float*)d_in[6];
  const float* fb2  = (const float*)d_in[7];
  const float* gw0  = (const float*)d_in[8];
  const float* gb0  = (const float*)d_in[9];
  const float* gw1  = (const float*)d_in[10];
  const float* gb1  = (const float*)d_in[11];
  const float* gw2  = (const float*)d_in[12];
  const float* gb2  = (const float*)d_in[13];
  const float* fsc  = (const float*)d_in[14];
  const float* gsc  = (const float*)d_in[15];
  const float* rwh  = (const float*)d_in[16];
  const float* rwx  = (const float*)d_in[17];
  const float* rnb  = (const float*)d_in[18];
  const float* ow0  = (const float*)d_in[19];
  const float* ob0  = (const float*)d_in[20];
  const float* ow1  = (const float*)d_in[21];
  const float* ob1  = (const float*)d_in[22];
  const float* ow2  = (const float*)d_in[23];
  const float* ob2  = (const float*)d_in[24];
  float* ws   = (float*)d_ws;
  float* outp = (float*)d_out;

  prep_transpose<<<(WS_TOTAL + 255)/256, 256, 0, stream>>>(
      fw0, fw1, fw2, gw0, gw1, gw2, rwh, rwx, ow0, ow1, ow2, ws);
  ace_main<<<BATCH, 256, 0, stream>>>(
      ts, obs, fb0, fb1, fb2, gb0, gb1, gb2, fsc, gsc, rnb, ob0, ob1, ob2, ws, outp);
}

// Round 2
// 6202.643 us; speedup vs baseline: 2.7892x; 2.7892x over previous
//
#include <hip/hip_runtime.h>
#include <hip/hip_bf16.h>

#define DH    64
#define INW   32
#define OUTW  8
#define WIDW  128
#define BATCH 128
#define SEQN  16
#define NSUB  4
#define NT    1024

// workspace layout (float/u32 slots)
#define OFF_GW2B 0        // u32[k2*4096 + r]: bf16 pair (k=2*k2, 2*k2+1) of row r; 64*4096
#define OFF_FW0T 262144   // [k*128 + o], 65x128
#define OFF_GW0T 270464
#define OFF_FW1T 278784   // [k*128 + o], 128x128
#define OFF_GW1T 295168
#define OFF_FW2T 311552   // [k*64 + o], 128x64
#define OFF_RWHT 319744   // [k*64 + o], 64x64
#define OFF_RWXT 323840   // [k*64 + o], 32x64
#define OFF_OW0T 325888   // [k*128 + o], 64x128
#define OFF_OW1T 334080   // [k*128 + o], 128x128
#define OFF_OW2T 350464   // [k*8 + o], 128x8
#define WS_TOTAL 351488

__device__ __forceinline__ float fast_tanh(float x){
  float ax = fabsf(x);
  float e  = __expf(-2.f*ax);
  float r  = __fdividef(1.f - e, 1.f + e);
  return copysignf(r, x);
}
__device__ __forceinline__ float fast_silu(float x){
  return x * __fdividef(1.f, 1.f + __expf(-x));
}
__device__ __forceinline__ unsigned int f2bf_rne(float x){
  unsigned int u = __float_as_uint(x);
  return (u + 0x7fffu + ((u >> 16) & 1u)) >> 16;   // RNE to bf16 (weights finite)
}

__global__ void prep_transpose(const float* __restrict__ fw0, const float* __restrict__ fw1,
                               const float* __restrict__ fw2, const float* __restrict__ gw0,
                               const float* __restrict__ gw1, const float* __restrict__ gw2,
                               const float* __restrict__ rwh, const float* __restrict__ rwx,
                               const float* __restrict__ ow0, const float* __restrict__ ow1,
                               const float* __restrict__ ow2, float* __restrict__ ws)
{
  int i = blockIdx.x * 256 + threadIdx.x;
  if (i >= WS_TOTAL) return;
  if (i < OFF_FW0T){            // bf16-packed gw2: u32[k2*4096 + r]
    int k2 = i >> 12, r = i & 4095;
    unsigned int lo = f2bf_rne(gw2[r*128 + 2*k2]);
    unsigned int hi = f2bf_rne(gw2[r*128 + 2*k2 + 1]);
    ((unsigned int*)ws)[i] = lo | (hi << 16);
  }
  else if (i < OFF_GW0T){ int j=i-OFF_FW0T; int o=j&127, k=j>>7; ws[i]=fw0[o*65+k]; }
  else if (i < OFF_FW1T){ int j=i-OFF_GW0T; int o=j&127, k=j>>7; ws[i]=gw0[o*65+k]; }
  else if (i < OFF_GW1T){ int j=i-OFF_FW1T; int o=j&127, k=j>>7; ws[i]=fw1[o*128+k]; }
  else if (i < OFF_FW2T){ int j=i-OFF_GW1T; int o=j&127, k=j>>7; ws[i]=gw1[o*128+k]; }
  else if (i < OFF_RWHT){ int j=i-OFF_FW2T; int o=j&63,  k=j>>6; ws[i]=fw2[o*128+k]; }
  else if (i < OFF_RWXT){ int j=i-OFF_RWHT; int o=j&63,  k=j>>6; ws[i]=rwh[o*64+k]; }
  else if (i < OFF_OW0T){ int j=i-OFF_RWXT; int o=j&63,  k=j>>6; ws[i]=rwx[o*32+k]; }
  else if (i < OFF_OW1T){ int j=i-OFF_OW0T; int o=j&127, k=j>>7; ws[i]=ow0[o*64+k]; }
  else if (i < OFF_OW2T){ int j=i-OFF_OW1T; int o=j&127, k=j>>7; ws[i]=ow1[o*128+k]; }
  else                  { int j=i-OFF_OW2T; int o=j&7,   k=j>>3; ws[i]=ow2[o*128+k]; }
}

__global__ __launch_bounds__(NT) void ace_main(
    const float* __restrict__ ts,
    const float* __restrict__ obs,
    const float* __restrict__ fb0, const float* __restrict__ fb1, const float* __restrict__ fb2,
    const float* __restrict__ gb0, const float* __restrict__ gb1, const float* __restrict__ gb2,
    const float* __restrict__ fsc, const float* __restrict__ gsc,
    const float* __restrict__ rnnb,
    const float* __restrict__ ob0, const float* __restrict__ ob1, const float* __restrict__ ob2,
    const float* __restrict__ ws,
    float* __restrict__ outp)
{
  constexpr float ATc[5][5] = {
    {0.161f, 0.f, 0.f, 0.f, 0.f},
    {-0.008480655492356989f, 0.335480655492357f, 0.f, 0.f, 0.f},
    {2.8971530571054935f, -6.359448489975075f, 4.3622954328695815f, 0.f, 0.f},
    {5.325864828439257f, -11.748883564062828f, 7.4955393428898365f, -0.09249506636175525f, 0.f},
    {5.86145544294642f, -12.92096931784711f, 8.159367898576159f, -0.071584973281401f, -0.028269050394068383f}};
  constexpr float CTc[6] = {0.f, 0.161f, 0.327f, 0.9f, 0.9800255409045097f, 1.f};
  constexpr float BTc[6] = {0.09646076681806523f, 0.01f, 0.4798896504144996f,
                            1.379008574103742f, -3.290069515436081f, 2.324710524099774f};

  const int tid = threadIdx.x;
  const int b   = blockIdx.x;
  const int row = tid >> 4;        // a-row 0..63 (owns cols 4*c3..4*c3+3)
  const int c3  = tid & 15;

  const unsigned int* gw2b = (const unsigned int*)ws;   // OFF_GW2B
  const float* fw0T = ws + OFF_FW0T;
  const float* gw0T = ws + OFF_GW0T;
  const float* fw1T = ws + OFF_FW1T;
  const float* gw1T = ws + OFF_GW1T;
  const float* fw2T = ws + OFF_FW2T;
  const float* rwhT = ws + OFF_RWHT;
  const float* rwxT = ws + OFF_RWXT;
  const float* ow0T = ws + OFF_OW0T;
  const float* ow1T = ws + OFF_OW1T;
  const float* ow2T = ws + OFF_OW2T;

  __shared__ __align__(16) float h_st[DH];
  __shared__ __align__(16) float h_b[DH];
  __shared__ __align__(16) float inp[DH+1];
  __shared__ __align__(16) float zf0[WIDW], zg0[WIDW], zf1[WIDW], zg1[WIDW];
  __shared__ float red;

  float ka[6][4];     // a-rate stages, element e = 4*tid + i (rows contiguous per thread)
  float a_b[4];       // a-state base
  float khreg[6];     // h-rate stages (valid on c3==0 threads, o=row)
  const float4 gb2v = *(const float4*)&gb2[4*tid];
  const float sf = fsc[0], sg = gsc[0];

  const int  o01 = (tid >> 2) & 127;   // trunk output index
  const int  p01 = tid & 3;            // trunk k-part
  const bool isf = tid < 512;          // f-net vs g-net half

  auto field_eval = [&](float t, const float (&a_s)[4], float& kh_out, float (&ka_out)[4]){
    // ---- softmax row (from registers; 16-lane groups = one a-row)
    {
      float m = fmaxf(fmaxf(a_s[0], a_s[1]), fmaxf(a_s[2], a_s[3]));
      m = fmaxf(m, __shfl_xor(m, 1, 64));
      m = fmaxf(m, __shfl_xor(m, 2, 64));
      m = fmaxf(m, __shfl_xor(m, 4, 64));
      m = fmaxf(m, __shfl_xor(m, 8, 64));
      const float4 hv = *(const float4*)&h_st[4*c3];
      float e0 = __expf(a_s[0]-m), e1 = __expf(a_s[1]-m);
      float e2 = __expf(a_s[2]-m), e3 = __expf(a_s[3]-m);
      float es = (e0+e1) + (e2+e3);
      float hs = fmaf(e0,hv.x, fmaf(e1,hv.y, fmaf(e2,hv.z, e3*hv.w)));
      es += __shfl_xor(es, 1, 64); hs += __shfl_xor(hs, 1, 64);
      es += __shfl_xor(es, 2, 64); hs += __shfl_xor(hs, 2, 64);
      es += __shfl_xor(es, 4, 64); hs += __shfl_xor(hs, 4, 64);
      es += __shfl_xor(es, 8, 64); hs += __shfl_xor(hs, 8, 64);
      if (c3 == 0) inp[row] = __fdividef(hs, es);
      if (tid == 0) inp[DH] = t;
    }
    __syncthreads();
    { // ---- layer 0 (65 -> 128), split-K over 4 lanes, f/g in parallel halves
      const float* wT = isf ? fw0T : gw0T;
      const float* bb = isf ? fb0 : gb0;
      float acc = (p01 == 0) ? bb[o01] : 0.f;
      const int k0 = p01*16 + (p01 > 0);           // 0,17,33,49
      const int kn = (p01 == 0) ? 17 : 16;
      for (int kk = 0; kk < kn; ++kk)
        acc = fmaf(wT[(k0+kk)*128 + o01], inp[k0+kk], acc);
      acc += __shfl_xor(acc, 1, 64);
      acc += __shfl_xor(acc, 2, 64);
      if (p01 == 0) (isf ? zf0 : zg0)[o01] = fast_silu(acc);
    }
    __syncthreads();
    { // ---- layer 1 (128 -> 128)
      const float* wT = isf ? fw1T : gw1T;
      const float* bb = isf ? fb1 : gb1;
      const float* zi = isf ? zf0 : zg0;
      float acc = (p01 == 0) ? bb[o01] : 0.f;
      const int k0 = p01*32;
      #pragma unroll 8
      for (int kk = 0; kk < 32; ++kk)
        acc = fmaf(wT[(k0+kk)*128 + o01], zi[k0+kk], acc);
      acc += __shfl_xor(acc, 1, 64);
      acc += __shfl_xor(acc, 2, 64);
      if (p01 == 0) (isf ? zf1 : zg1)[o01] = fast_silu(acc);
    }
    __syncthreads();
    { // ---- f head (64 outputs, 16 lanes each; kh kept in c3==0 registers)
      float acc = (c3 == 0) ? fb2[row] : 0.f;
      const int k0 = c3*8;
      #pragma unroll
      for (int kk = 0; kk < 8; ++kk)
        acc = fmaf(fw2T[(k0+kk)*64 + row], zf1[k0+kk], acc);
      acc += __shfl_xor(acc, 1, 64);
      acc += __shfl_xor(acc, 2, 64);
      acc += __shfl_xor(acc, 4, 64);
      acc += __shfl_xor(acc, 8, 64);
      if (c3 == 0) kh_out = sf * fast_tanh(acc);
    }
    { // ---- g head: 4096x128 GEMV, bf16-packed weights, dwordx4 per k-pair
      float a0 = 0.f, a1 = 0.f, a2 = 0.f, a3 = 0.f;
      const unsigned int* gp = gw2b + 4*tid;
      #pragma unroll 8
      for (int k2 = 0; k2 < 64; ++k2){
        const uint4  u  = *(const uint4*)(gp + k2*4096);
        const float2 zz = *(const float2*)&zg1[2*k2];
        a0 = fmaf(__uint_as_float(u.x << 16),          zz.x, a0);
        a0 = fmaf(__uint_as_float(u.x & 0xffff0000u),  zz.y, a0);
        a1 = fmaf(__uint_as_float(u.y << 16),          zz.x, a1);
        a1 = fmaf(__uint_as_float(u.y & 0xffff0000u),  zz.y, a1);
        a2 = fmaf(__uint_as_float(u.z << 16),          zz.x, a2);
        a2 = fmaf(__uint_as_float(u.z & 0xffff0000u),  zz.y, a2);
        a3 = fmaf(__uint_as_float(u.w << 16),          zz.x, a3);
        a3 = fmaf(__uint_as_float(u.w & 0xffff0000u),  zz.y, a3);
      }
      ka_out[0] = sg * fast_tanh(a0 + gb2v.x);
      ka_out[1] = sg * fast_tanh(a1 + gb2v.y);
      ka_out[2] = sg * fast_tanh(a2 + gb2v.z);
      ka_out[3] = sg * fast_tanh(a3 + gb2v.w);
    }
  };

  auto attn_from_h = [&](){
    if (tid < 64){
      float v = h_b[tid]; v = v*v;
      #pragma unroll
      for (int off = 32; off > 0; off >>= 1) v += __shfl_xor(v, off, 64);
      if (tid == 0) red = __fdividef(1.f, sqrtf(v) + 1e-8f);
    }
    __syncthreads();
    const float inv = red;
    const float  hr = h_b[row] * inv;
    const float4 hc = *(const float4*)&h_b[4*c3];
    a_b[0] = hr * (hc.x * inv);
    a_b[1] = hr * (hc.y * inv);
    a_b[2] = hr * (hc.z * inv);
    a_b[3] = hr * (hc.w * inv);
  };

  // ---- init: h0 = tanh(rnn_wx @ obs[0] + rnn_b); a0 = attn(h0)
  if (tid < 64){
    float acc = rnnb[tid];
    const float* x0 = obs + b*(SEQN*INW);
    #pragma unroll
    for (int k = 0; k < INW; ++k) acc = fmaf(rwxT[k*64 + tid], x0[k], acc);
    h_b[tid] = fast_tanh(acc);
  }
  attn_from_h();

  for (int n = 0; n < SEQN-1; ++n){
    const float t0  = ts[b*SEQN + n];
    const float t1  = ts[b*SEQN + n + 1];
    const float dtn = (t1 - t0) * 0.25f;

    for (int isub = 0; isub < NSUB; ++isub){
      const float tb = fmaf((float)isub, dtn, t0);
      if (c3 == 0) h_st[row] = h_b[row];
      __syncthreads();
      field_eval(tb, a_b, khreg[0], ka[0]);

      #pragma unroll
      for (int s = 0; s < 5; ++s){
        if (c3 == 0){
          float acc = 0.f;
          #pragma unroll
          for (int j = 0; j <= s; ++j) acc = fmaf(ATc[s][j], khreg[j], acc);
          h_st[row] = fmaf(dtn, acc, h_b[row]);
        }
        float a_s[4];
        #pragma unroll
        for (int i = 0; i < 4; ++i){
          float acc = 0.f;
          #pragma unroll
          for (int j = 0; j <= s; ++j) acc = fmaf(ATc[s][j], ka[j][i], acc);
          a_s[i] = fmaf(dtn, acc, a_b[i]);
        }
        __syncthreads();
        field_eval(fmaf(CTc[s+1], dtn, tb), a_s, khreg[s+1], ka[s+1]);
      }

      if (c3 == 0){
        float acc = 0.f;
        #pragma unroll
        for (int j = 0; j < 6; ++j) acc = fmaf(BTc[j], khreg[j], acc);
        h_b[row] = fmaf(dtn, acc, h_b[row]);
      }
      #pragma unroll
      for (int i = 0; i < 4; ++i){
        float acc = 0.f;
        #pragma unroll
        for (int j = 0; j < 6; ++j) acc = fmaf(BTc[j], ka[j][i], acc);
        a_b[i] = fmaf(dtn, acc, a_b[i]);
      }
    }

    // ---- RNN boundary
    __syncthreads();               // publish h_b (written by c3==0 threads)
    float hnew = 0.f;
    if (tid < 64){
      float acc = rnnb[tid];
      const float* x = obs + (b*SEQN + (n+1))*INW;
      #pragma unroll
      for (int k = 0; k < INW; ++k) acc = fmaf(rwxT[k*64 + tid], x[k], acc);
      #pragma unroll 8
      for (int k = 0; k < DH; ++k)  acc = fmaf(rwhT[k*64 + tid], h_b[k], acc);
      hnew = fast_tanh(acc);
    }
    __syncthreads();               // old h_b reads complete
    if (tid < 64) h_b[tid] = hnew;
    attn_from_h();                 // internal barrier publishes h_b/red
  }

  // ---- output MLP (tanh)
  if (tid < 128){
    float acc = ob0[tid];
    #pragma unroll 8
    for (int k = 0; k < DH; ++k) acc = fmaf(ow0T[k*128 + tid], h_b[k], acc);
    zf0[tid] = fast_tanh(acc);
  }
  __syncthreads();
  if (tid < 128){
    float acc = ob1[tid];
    #pragma unroll 8
    for (int k = 0; k < WIDW; ++k) acc = fmaf(ow1T[k*128 + tid], zf0[k], acc);
    zf1[tid] = fast_tanh(acc);
  }
  __syncthreads();
  if (tid < OUTW){
    float acc = ob2[tid];
    #pragma unroll 8
    for (int k = 0; k < WIDW; ++k) acc = fmaf(ow2T[k*8 + tid], zf1[k], acc);
    outp[b*OUTW + tid] = acc;
  }
}

extern "C" void kernel_launch(void* const* d_in, const int* in_sizes, int n_in,
                              void* d_out, int out_size, void* d_ws, size_t ws_size,
                              hipStream_t stream)
{
  const float* ts   = (const float*)d_in[0];
  const float* obs  = (const float*)d_in[1];
  const float* fw0  = (const float*)d_in[2];
  const float* fb0  = (const float*)d_in[3];
  const float* fw1  = (const float*)d_in[4];
  const float* fb1  = (const float*)d_in[5];
  const float* fw2  = (const float*)d_in[6];
  const float* fb2  = (const float*)d_in[7];
  const float* gw0  = (const float*)d_in[8];
  const float* gb0  = (const float*)d_in[9];
  const float* gw1  = (const float*)d_in[10];
  const float* gb1  = (const float*)d_in[11];
  const float* gw2  = (const float*)d_in[12];
  const float* gb2  = (const float*)d_in[13];
  const float* fsc  = (const float*)d_in[14];
  const float* gsc  = (const float*)d_in[15];
  const float* rwh  = (const float*)d_in[16];
  const float* rwx  = (const float*)d_in[17];
  const float* rnb  = (const float*)d_in[18];
  const float* ow0  = (const float*)d_in[19];
  const float* ob0  = (const float*)d_in[20];
  const float* ow1  = (const float*)d_in[21];
  const float* ob1  = (const float*)d_in[22];
  const float* ow2  = (const float*)d_in[23];
  const float* ob2  = (const float*)d_in[24];
  float* ws   = (float*)d_ws;
  float* outp = (float*)d_out;

  prep_transpose<<<(WS_TOTAL + 255)/256, 256, 0, stream>>>(
      fw0, fw1, fw2, gw0, gw1, gw2, rwh, rwx, ow0, ow1, ow2, ws);
  ace_main<<<BATCH, NT, 0, stream>>>(
      ts, obs, fb0, fb1, fb2, gb0, gb1, gb2, fsc, gsc, rnb, ob0, ob1, ob2, ws, outp);
}